// Round 19
// baseline (1118.599 us; speedup 1.0000x reference)
//
#include <hip/hip_runtime.h>
#include <math.h>

// Chamfer distance via MFMA, B=8, N=8192, fp32 in, fp32 scalar out.
//
// d(q,t) = |q|^2 + |t|^2 - 2 q.t  ==  dot(A_row(q), B_col(t)) with K=5:
//   A_row = (-2x_q, -2y_q, -2z_q, 1, |q|^2),  B_col = (x_t, y_t, z_t, |t|^2, 1)
// in f16 (zero-padded to K=16).  One v_mfma_f32_32x32x16_f16 -> a 32x32 tile
// of complete squared distances in fp32.
//
// R18 — SYMMETRY: the dir=1 distance matrix is the transpose of dir=0, so
// each tile yields row-mins for xyz1 (register accumulators, as before)
// AND col-mins for xyz2 (per-iter umin tree over the lane's 16 rows +
// shfl32 + LDS atomicMin into a block-local colmin array).  This halves
// MFMA, LDS-read, and staging work; fold work stays ~same.  Col extraction
// is layout-safe: a lane's 16 results all belong to col lane&31.
//
// prep:    clouds -> packed f16 form (x,y,z,n,1,0,0,0); bits = +inf.
// main:    512 blocks = batch(8) x rowblock(32) x colsplit(2); 4 waves x
//          2 strips = 256 xyz1-rows/block over 4096 xyz2-cols.  Both sides
//          merged via atomicMin on nonneg-float bit patterns (exact,
//          order-independent => deterministic).
// reduce1: sqrt(max(min,EPS)) + per-256 block sums.   final: sum/TOTALQ.

#define NPTS   8192
#define NB     8
#define NPC    (NB * NPTS)         // 65536
#define BLOCK  256
#define CHUNK  1024
#define CS     2                   // col splits
#define COLS   (NPTS / CS)         // 4096 cols per block
#define TOTALQ (2 * NPC)           // 131072
#define EPSV   1e-12f

typedef _Float16 v8h  __attribute__((ext_vector_type(8)));
typedef float    v16f __attribute__((ext_vector_type(16)));

__global__ __launch_bounds__(256) void chamfer_prep(
    const float* __restrict__ xyz1, const float* __restrict__ xyz2,
    v8h* __restrict__ form, unsigned* __restrict__ bits)
{
    const int gid = blockIdx.x * 256 + threadIdx.x;      // [0, TOTALQ)
    const float* __restrict__ src = (gid < NPC) ? xyz1 : xyz2;
    const int i = (gid < NPC) ? gid : gid - NPC;
    float x = src[3 * i], y = src[3 * i + 1], z = src[3 * i + 2];
    _Float16 xh = (_Float16)x, yh = (_Float16)y, zh = (_Float16)z;
    float xf = (float)xh, yf = (float)yh, zf = (float)zh;
    float n = fmaf(xf, xf, fmaf(yf, yf, zf * zf));
    v8h bv = {};
    bv[0] = xh; bv[1] = yh; bv[2] = zh;
    bv[3] = (_Float16)n; bv[4] = (_Float16)1.0f;
    form[gid] = bv;
    bits[gid] = 0x7F7F7F7FU;       // 3.39e38f: "+inf" for nonneg uint-min
}

#define MFMA(va, vb) __builtin_amdgcn_mfma_f32_32x32x16_f16((va), (vb), vzero, 0, 0, 0)

__device__ __forceinline__ unsigned umin2(unsigned a, unsigned b) {
    return a < b ? a : b;
}
__device__ __forceinline__ unsigned ubit(float f) {
    return __builtin_bit_cast(unsigned, f);
}

// Balanced min-tree over one v16f (15 umin, depth 4).
__device__ __forceinline__ unsigned tmin16(const v16f& p) {
    unsigned m0 = umin2(umin2(ubit(p[0]),  ubit(p[1])),  umin2(ubit(p[2]),  ubit(p[3])));
    unsigned m1 = umin2(umin2(ubit(p[4]),  ubit(p[5])),  umin2(ubit(p[6]),  ubit(p[7])));
    unsigned m2 = umin2(umin2(ubit(p[8]),  ubit(p[9])),  umin2(ubit(p[10]), ubit(p[11])));
    unsigned m3 = umin2(umin2(ubit(p[12]), ubit(p[13])), umin2(ubit(p[14]), ubit(p[15])));
    return umin2(umin2(m0, m1), umin2(m2, m3));
}

__global__ __launch_bounds__(BLOCK, 2) void chamfer_mfma_sym(
    const v8h* __restrict__ form, unsigned* __restrict__ bits)
{
    const int bid = blockIdx.x;             // [0, 512)
    const int cs  = bid & (CS - 1);
    const int rbg = bid >> 1;               // [0, 256) global rowblock
    const int b   = rbg >> 5;               // batch
    const int rbi = rbg & 31;               // rowblock within batch

    const v8h* __restrict__ qf = form + (size_t)b * NPTS;          // xyz1 side
    const v8h* __restrict__ tf = form + NPC + (size_t)b * NPTS + cs * COLS;

    const int tid  = threadIdx.x;
    const int lane = tid & 63;
    const int w    = tid >> 6;              // wave 0..3, two 32-row strips each
    const int c31  = lane & 31;
    const int rowbase = rbi * 256;

    // A fragments: lanes<32 carry k=0..7 (5 live slots); lanes>=32 carry
    // k=8..15 which are all zero.
    v8h a0 = {}, a1 = {};
    if (lane < 32) {
        const _Float16 m2 = (_Float16)(-2.0f);
        v8h f = qf[rowbase + w * 64 + lane];
        a0[0] = m2 * f[0]; a0[1] = m2 * f[1]; a0[2] = m2 * f[2];
        a0[3] = (_Float16)1.0f; a0[4] = f[3];
        f = qf[rowbase + w * 64 + 32 + lane];
        a1[0] = m2 * f[0]; a1[1] = m2 * f[1]; a1[2] = m2 * f[2];
        a1[3] = (_Float16)1.0f; a1[4] = f[3];
    }

    unsigned rm0[16], rm1[16];
#pragma unroll
    for (int r = 0; r < 16; ++r) { rm0[r] = 0x7F7F7F7FU; rm1[r] = 0x7F7F7F7FU; }

    __shared__ v8h bsh[CHUNK];              // 16 KB staging
    __shared__ unsigned colmin[COLS];       // 16 KB block-local col-mins
    for (int i = tid; i < COLS; i += BLOCK) colmin[i] = 0x7F7F7F7FU;

    const v16f vzero = {};

    for (int ch = 0; ch < COLS / CHUNK; ++ch) {
        __syncthreads();
        const v8h* __restrict__ g = tf + ch * CHUNK;
#pragma unroll
        for (int k = 0; k < CHUNK / BLOCK; ++k)
            bsh[k * BLOCK + tid] = g[k * BLOCK + tid];   // b128 in, b128 out
        __syncthreads();

#pragma unroll
        for (int cc = 0; cc < CHUNK / 64; ++cc) {
            const v8h b0 = bsh[cc * 64 + c31];           // broadcast b128
            const v8h b1 = bsh[cc * 64 + 32 + c31];
            v16f p0 = MFMA(a0, b0);
            v16f q0 = MFMA(a0, b1);
            v16f p1 = MFMA(a1, b0);
            v16f q1 = MFMA(a1, b1);

            // Row-side fold (xyz1 mins, accumulated in registers).
#pragma unroll
            for (int r = 0; r < 16; ++r)
                rm0[r] = umin2(rm0[r], umin2(ubit(p0[r]), ubit(q0[r])));
#pragma unroll
            for (int r = 0; r < 16; ++r)
                rm1[r] = umin2(rm1[r], umin2(ubit(p1[r]), ubit(q1[r])));

            // Col-side fold (xyz2 mins): min over this block's 64 rows.
            unsigned cm0 = umin2(tmin16(p0), tmin16(p1));      // b0's col
            unsigned cm1 = umin2(tmin16(q0), tmin16(q1));      // b1's col
            cm0 = umin2(cm0, __shfl_xor(cm0, 32));
            cm1 = umin2(cm1, __shfl_xor(cm1, 32));
            if (lane < 32) {
                const int cl = ch * CHUNK + cc * 64 + c31;
                atomicMin(&colmin[cl], cm0);
                atomicMin(&colmin[cl + 32], cm1);
            }
        }
    }

    // Row-side epilogue: butterfly across the 32 lanes sharing each row,
    // one atomicMin per row (partial over cols: CS=2 blocks merge).
    unsigned* rdst = bits + (size_t)b * NPTS + rowbase;
#pragma unroll
    for (int s = 0; s < 2; ++s) {
#pragma unroll
        for (int r = 0; r < 16; ++r) {
            unsigned u = s ? rm1[r] : rm0[r];
            u = umin2(u, __shfl_xor(u, 1));
            u = umin2(u, __shfl_xor(u, 2));
            u = umin2(u, __shfl_xor(u, 4));
            u = umin2(u, __shfl_xor(u, 8));
            u = umin2(u, __shfl_xor(u, 16));
            if ((lane & 31) == 0) {
                int row_local = w * 64 + s * 32 + (r & 3) + 8 * (r >> 2) + 4 * (lane >> 5);
                atomicMin(rdst + row_local, u);
            }
        }
    }

    // Col-side epilogue: sweep block-local colmin into global bits
    // (partial over rows: 32 rowblocks merge).
    __syncthreads();
    unsigned* cdst = bits + NPC + (size_t)b * NPTS + cs * COLS;
    for (int i = tid; i < COLS; i += BLOCK)
        atomicMin(cdst + i, colmin[i]);
}

__global__ __launch_bounds__(BLOCK) void chamfer_reduce1(
    const unsigned* __restrict__ bits,   // [TOTALQ]
    float* __restrict__ sums)            // [512]
{
    const int idx = blockIdx.x * BLOCK + threadIdx.x;
    float m = __uint_as_float(bits[idx]);
    float val = sqrtf(fmaxf(fmaxf(m, 0.0f), EPSV));

    __shared__ float red[BLOCK];
    red[threadIdx.x] = val;
    __syncthreads();
    for (int s = BLOCK / 2; s > 0; s >>= 1) {
        if (threadIdx.x < s) red[threadIdx.x] += red[threadIdx.x + s];
        __syncthreads();
    }
    if (threadIdx.x == 0) sums[blockIdx.x] = red[0];
}

#define NSUMS (TOTALQ / BLOCK)   // 512

__global__ __launch_bounds__(NSUMS) void chamfer_finalize(
    const float* __restrict__ sums, float* __restrict__ out)
{
    __shared__ float red[NSUMS];
    red[threadIdx.x] = sums[threadIdx.x];
    __syncthreads();
    for (int s = NSUMS / 2; s > 0; s >>= 1) {
        if (threadIdx.x < s) red[threadIdx.x] += red[threadIdx.x + s];
        __syncthreads();
    }
    if (threadIdx.x == 0) out[0] = red[0] * (1.0f / (float)TOTALQ);
}

extern "C" void kernel_launch(void* const* d_in, const int* in_sizes, int n_in,
                              void* d_out, int out_size, void* d_ws, size_t ws_size,
                              hipStream_t stream) {
    const float* xyz1 = (const float*)d_in[0];
    const float* xyz2 = (const float*)d_in[1];
    float* out = (float*)d_out;

    v8h*      formbuf = (v8h*)d_ws;                      // TOTALQ v8h = 2 MB
    unsigned* bitsbuf = (unsigned*)(formbuf + TOTALQ);   // TOTALQ u32 = 512 KB
    float*    sums    = (float*)(bitsbuf + TOTALQ);      // 512 floats

    chamfer_prep<<<TOTALQ / 256, 256, 0, stream>>>(xyz1, xyz2, formbuf, bitsbuf);
    chamfer_mfma_sym<<<NB * 32 * CS, BLOCK, 0, stream>>>(formbuf, bitsbuf);
    chamfer_reduce1<<<TOTALQ / BLOCK, BLOCK, 0, stream>>>(bitsbuf, sums);
    chamfer_finalize<<<1, NSUMS, 0, stream>>>(sums, out);
}

// Round 20
// 72.241 us; speedup vs baseline: 15.4843x; 15.4843x over previous
//
#include <hip/hip_runtime.h>
#include <math.h>

// Chamfer distance via MFMA, B=8, N=8192, fp32 in, fp32 scalar out.
//
// d(q,t) = |q|^2 + |t|^2 - 2 q.t  ==  dot(A_row(q), B_col(t)) with K=5:
//   A_row = (-2x_q, -2y_q, -2z_q, 1, |q|^2),  B_col = (x_t, y_t, z_t, |t|^2, 1)
// in f16 (zero-padded to K=16).  One v_mfma_f32_32x32x16_f16 -> a 32x32 tile
// of complete squared distances in fp32.
//
// R19 — SYMMETRY (R18 repaired): each tile serves BOTH directions (row-mins
// for xyz1 in registers; col-mins for xyz2 via in-lane tree + shfl32 + LDS
// atomicMin).  Halves MFMA, LDS-read, staging work.  R18's spill fixed by
// folding IMMEDIATELY after each MFMA pair (only 2 result tiles live, col
// partials cm0/cm1 carry across strips) + __launch_bounds__(256,3) for a
// 170-VGPR budget.  Live set ~95 regs.  Spill canary: FETCH must stay ~5MB.
//
// prep:    clouds -> packed f16 form (x,y,z,n,1,0,0,0); bits = +inf.
// main:    512 blocks = batch(8) x rowblock(32) x colsplit(2); 4 waves x
//          2 strips = 256 xyz1-rows/block over 4096 xyz2-cols.
// reduce1: sqrt(max(min,EPS)) + per-256 block sums.   final: sum/TOTALQ.

#define NPTS   8192
#define NB     8
#define NPC    (NB * NPTS)         // 65536
#define BLOCK  256
#define CHUNK  1024
#define CS     2                   // col splits
#define COLS   (NPTS / CS)         // 4096 cols per block
#define TOTALQ (2 * NPC)           // 131072
#define EPSV   1e-12f

typedef _Float16 v8h  __attribute__((ext_vector_type(8)));
typedef float    v16f __attribute__((ext_vector_type(16)));

__global__ __launch_bounds__(256) void chamfer_prep(
    const float* __restrict__ xyz1, const float* __restrict__ xyz2,
    v8h* __restrict__ form, unsigned* __restrict__ bits)
{
    const int gid = blockIdx.x * 256 + threadIdx.x;      // [0, TOTALQ)
    const float* __restrict__ src = (gid < NPC) ? xyz1 : xyz2;
    const int i = (gid < NPC) ? gid : gid - NPC;
    float x = src[3 * i], y = src[3 * i + 1], z = src[3 * i + 2];
    _Float16 xh = (_Float16)x, yh = (_Float16)y, zh = (_Float16)z;
    float xf = (float)xh, yf = (float)yh, zf = (float)zh;
    float n = fmaf(xf, xf, fmaf(yf, yf, zf * zf));
    v8h bv = {};
    bv[0] = xh; bv[1] = yh; bv[2] = zh;
    bv[3] = (_Float16)n; bv[4] = (_Float16)1.0f;
    form[gid] = bv;
    bits[gid] = 0x7F7F7F7FU;       // 3.39e38f: "+inf" for nonneg uint-min
}

#define MFMA(va, vb) __builtin_amdgcn_mfma_f32_32x32x16_f16((va), (vb), vzero, 0, 0, 0)

__device__ __forceinline__ unsigned umin2(unsigned a, unsigned b) {
    return a < b ? a : b;
}
__device__ __forceinline__ unsigned ubit(float f) {
    return __builtin_bit_cast(unsigned, f);
}

// Balanced min-tree over one v16f (15 umin, depth 4).
__device__ __forceinline__ unsigned tmin16(const v16f& p) {
    unsigned m0 = umin2(umin2(ubit(p[0]),  ubit(p[1])),  umin2(ubit(p[2]),  ubit(p[3])));
    unsigned m1 = umin2(umin2(ubit(p[4]),  ubit(p[5])),  umin2(ubit(p[6]),  ubit(p[7])));
    unsigned m2 = umin2(umin2(ubit(p[8]),  ubit(p[9])),  umin2(ubit(p[10]), ubit(p[11])));
    unsigned m3 = umin2(umin2(ubit(p[12]), ubit(p[13])), umin2(ubit(p[14]), ubit(p[15])));
    return umin2(umin2(m0, m1), umin2(m2, m3));
}

__global__ __launch_bounds__(BLOCK, 3) void chamfer_mfma_sym(
    const v8h* __restrict__ form, unsigned* __restrict__ bits)
{
    const int bid = blockIdx.x;             // [0, 512)
    const int cs  = bid & (CS - 1);
    const int rbg = bid >> 1;               // [0, 256) global rowblock
    const int b   = rbg >> 5;               // batch
    const int rbi = rbg & 31;               // rowblock within batch

    const v8h* __restrict__ qf = form + (size_t)b * NPTS;          // xyz1 side
    const v8h* __restrict__ tf = form + NPC + (size_t)b * NPTS + cs * COLS;

    const int tid  = threadIdx.x;
    const int lane = tid & 63;
    const int w    = tid >> 6;              // wave 0..3, two 32-row strips each
    const int c31  = lane & 31;
    const int rowbase = rbi * 256;

    // A fragments: lanes<32 carry k=0..7 (5 live slots); lanes>=32 carry
    // k=8..15 which are all zero.
    v8h a0 = {}, a1 = {};
    if (lane < 32) {
        const _Float16 m2 = (_Float16)(-2.0f);
        v8h f = qf[rowbase + w * 64 + lane];
        a0[0] = m2 * f[0]; a0[1] = m2 * f[1]; a0[2] = m2 * f[2];
        a0[3] = (_Float16)1.0f; a0[4] = f[3];
        f = qf[rowbase + w * 64 + 32 + lane];
        a1[0] = m2 * f[0]; a1[1] = m2 * f[1]; a1[2] = m2 * f[2];
        a1[3] = (_Float16)1.0f; a1[4] = f[3];
    }

    unsigned rm0[16], rm1[16];
#pragma unroll
    for (int r = 0; r < 16; ++r) { rm0[r] = 0x7F7F7F7FU; rm1[r] = 0x7F7F7F7FU; }

    __shared__ v8h bsh[CHUNK];              // 16 KB staging
    __shared__ unsigned colmin[COLS];       // 16 KB block-local col-mins
    for (int i = tid; i < COLS; i += BLOCK) colmin[i] = 0x7F7F7F7FU;

    const v16f vzero = {};

    for (int ch = 0; ch < COLS / CHUNK; ++ch) {
        __syncthreads();
        const v8h* __restrict__ g = tf + ch * CHUNK;
#pragma unroll
        for (int k = 0; k < CHUNK / BLOCK; ++k)
            bsh[k * BLOCK + tid] = g[k * BLOCK + tid];   // b128 in, b128 out
        __syncthreads();

#pragma unroll 2
        for (int cc = 0; cc < CHUNK / 64; ++cc) {
            const v8h b0 = bsh[cc * 64 + c31];           // broadcast b128
            const v8h b1 = bsh[cc * 64 + 32 + c31];
            unsigned cm0, cm1;
            // Strip 0: compute, then fold BOTH sides before strip 1 so only
            // two result tiles are ever live (R18 spill fix).
            {
                v16f p = MFMA(a0, b0);
                v16f q = MFMA(a0, b1);
#pragma unroll
                for (int r = 0; r < 16; ++r)
                    rm0[r] = umin2(rm0[r], umin2(ubit(p[r]), ubit(q[r])));
                cm0 = tmin16(p);
                cm1 = tmin16(q);
            }
            // Strip 1.
            {
                v16f p = MFMA(a1, b0);
                v16f q = MFMA(a1, b1);
#pragma unroll
                for (int r = 0; r < 16; ++r)
                    rm1[r] = umin2(rm1[r], umin2(ubit(p[r]), ubit(q[r])));
                cm0 = umin2(cm0, tmin16(p));
                cm1 = umin2(cm1, tmin16(q));
            }
            // Col-side: combine lane halves (rows +4) and publish.
            cm0 = umin2(cm0, __shfl_xor(cm0, 32));
            cm1 = umin2(cm1, __shfl_xor(cm1, 32));
            if (lane < 32) {
                const int cl = ch * CHUNK + cc * 64 + c31;
                atomicMin(&colmin[cl], cm0);
                atomicMin(&colmin[cl + 32], cm1);
            }
        }
    }

    // Row-side epilogue: butterfly across the 32 lanes sharing each row,
    // one atomicMin per row (CS=2 blocks merge).
    unsigned* rdst = bits + (size_t)b * NPTS + rowbase;
#pragma unroll
    for (int s = 0; s < 2; ++s) {
#pragma unroll
        for (int r = 0; r < 16; ++r) {
            unsigned u = s ? rm1[r] : rm0[r];
            u = umin2(u, __shfl_xor(u, 1));
            u = umin2(u, __shfl_xor(u, 2));
            u = umin2(u, __shfl_xor(u, 4));
            u = umin2(u, __shfl_xor(u, 8));
            u = umin2(u, __shfl_xor(u, 16));
            if ((lane & 31) == 0) {
                int row_local = w * 64 + s * 32 + (r & 3) + 8 * (r >> 2) + 4 * (lane >> 5);
                atomicMin(rdst + row_local, u);
            }
        }
    }

    // Col-side epilogue: sweep block-local colmin into global bits
    // (32 rowblocks merge per col).
    __syncthreads();
    unsigned* cdst = bits + NPC + (size_t)b * NPTS + cs * COLS;
    for (int i = tid; i < COLS; i += BLOCK)
        atomicMin(cdst + i, colmin[i]);
}

__global__ __launch_bounds__(BLOCK) void chamfer_reduce1(
    const unsigned* __restrict__ bits,   // [TOTALQ]
    float* __restrict__ sums)            // [512]
{
    const int idx = blockIdx.x * BLOCK + threadIdx.x;
    float m = __uint_as_float(bits[idx]);
    float val = sqrtf(fmaxf(fmaxf(m, 0.0f), EPSV));

    __shared__ float red[BLOCK];
    red[threadIdx.x] = val;
    __syncthreads();
    for (int s = BLOCK / 2; s > 0; s >>= 1) {
        if (threadIdx.x < s) red[threadIdx.x] += red[threadIdx.x + s];
        __syncthreads();
    }
    if (threadIdx.x == 0) sums[blockIdx.x] = red[0];
}

#define NSUMS (TOTALQ / BLOCK)   // 512

__global__ __launch_bounds__(NSUMS) void chamfer_finalize(
    const float* __restrict__ sums, float* __restrict__ out)
{
    __shared__ float red[NSUMS];
    red[threadIdx.x] = sums[threadIdx.x];
    __syncthreads();
    for (int s = NSUMS / 2; s > 0; s >>= 1) {
        if (threadIdx.x < s) red[threadIdx.x] += red[threadIdx.x + s];
        __syncthreads();
    }
    if (threadIdx.x == 0) out[0] = red[0] * (1.0f / (float)TOTALQ);
}

extern "C" void kernel_launch(void* const* d_in, const int* in_sizes, int n_in,
                              void* d_out, int out_size, void* d_ws, size_t ws_size,
                              hipStream_t stream) {
    const float* xyz1 = (const float*)d_in[0];
    const float* xyz2 = (const float*)d_in[1];
    float* out = (float*)d_out;

    v8h*      formbuf = (v8h*)d_ws;                      // TOTALQ v8h = 2 MB
    unsigned* bitsbuf = (unsigned*)(formbuf + TOTALQ);   // TOTALQ u32 = 512 KB
    float*    sums    = (float*)(bitsbuf + TOTALQ);      // 512 floats

    chamfer_prep<<<TOTALQ / 256, 256, 0, stream>>>(xyz1, xyz2, formbuf, bitsbuf);
    chamfer_mfma_sym<<<NB * 32 * CS, BLOCK, 0, stream>>>(formbuf, bitsbuf);
    chamfer_reduce1<<<TOTALQ / BLOCK, BLOCK, 0, stream>>>(bitsbuf, sums);
    chamfer_finalize<<<1, NSUMS, 0, stream>>>(sums, out);
}

// Round 21
// 45.547 us; speedup vs baseline: 24.5594x; 1.5861x over previous
//
#include <hip/hip_runtime.h>
#include <math.h>

// Chamfer distance via MFMA, B=8, N=8192, fp32 in, fp32 scalar out.
// FINAL (R15 restored — best of 20 rounds, 45.6 us total).
//
// d(q,t) = |q|^2 + |t|^2 - 2 q.t  ==  dot(A_row(q), B_col(t)) with K=5:
//   A_row = (-2x_q, -2y_q, -2z_q, 1, |q|^2),  B_col = (x_t, y_t, z_t, |t|^2, 1)
// in f16 (zero-padded to K=16).  One v_mfma_f32_32x32x16_f16 -> a 32x32 tile
// of complete squared distances in fp32.
//
// Measured decomposition (main kernel ~40 us): LDS-read ~10 + MFMA ~13 +
// fold-VALU ~14 + staging/sync — a serial pipe-work sum.  Ten structural
// variants (software pipelining, sched_barrier, inline-asm min3, occupancy
// 2->6 waves/SIMD, barrier-free free-run, DMA double-buffer, global-direct,
// transpose-symmetric) all nulled, raced, or spilled; fold floor is
// 1 umin/element and MFMA floor 13 us — this formulation's plateau.
//
// prep:   clouds -> packed f16 form (x,y,z,n,1,0,0,0); zero sum counter.
// main:   512 blocks = dir(2) x batch(8) x rowblock(32); 4 waves x 2 strips
//         = 256 rows/block, all 8192 cols -> rowmins block-final; epilogue
//         does sqrt + block-sum + ONE u64 fixed-point atomicAdd per block
//         (order-independent => deterministic).  u32 min fold (squared
//         dists are uint-monotone).
// final:  1 thread: out = counter / 2^26 / TOTALQ.

#define NPTS   8192
#define NB     8
#define NPC    (NB * NPTS)         // 65536
#define BLOCK  256
#define CHUNK  1024
#define COLS   NPTS                // all cols per block
#define TOTALQ (2 * NPC)           // 131072
#define EPSV   1e-12f
#define FXSCALE 67108864.0         // 2^26

typedef _Float16 v8h  __attribute__((ext_vector_type(8)));
typedef float    v16f __attribute__((ext_vector_type(16)));

__global__ __launch_bounds__(256) void chamfer_prep(
    const float* __restrict__ xyz1, const float* __restrict__ xyz2,
    v8h* __restrict__ form, unsigned long long* __restrict__ counter)
{
    const int gid = blockIdx.x * 256 + threadIdx.x;      // [0, TOTALQ)
    if (gid == 0) counter[0] = 0ULL;
    const float* __restrict__ src = (gid < NPC) ? xyz1 : xyz2;
    const int i = (gid < NPC) ? gid : gid - NPC;
    float x = src[3 * i], y = src[3 * i + 1], z = src[3 * i + 2];
    _Float16 xh = (_Float16)x, yh = (_Float16)y, zh = (_Float16)z;
    float xf = (float)xh, yf = (float)yh, zf = (float)zh;
    float n = fmaf(xf, xf, fmaf(yf, yf, zf * zf));
    v8h bv = {};
    bv[0] = xh; bv[1] = yh; bv[2] = zh;
    bv[3] = (_Float16)n; bv[4] = (_Float16)1.0f;
    form[gid] = bv;
}

#define MFMA(va, vb) __builtin_amdgcn_mfma_f32_32x32x16_f16((va), (vb), vzero, 0, 0, 0)

__device__ __forceinline__ unsigned umin2(unsigned a, unsigned b) {
    return a < b ? a : b;
}

__global__ __launch_bounds__(BLOCK, 4) void chamfer_mfma_min(
    const v8h* __restrict__ form, unsigned long long* __restrict__ counter)
{
    const int bid = blockIdx.x;             // [0, 512)
    const int rb  = bid & 31;
    const int b   = (bid >> 5) & 7;
    const int dir = (bid >> 8) & 1;

    const v8h* __restrict__ qf = form + (size_t)dir * NPC + (size_t)b * NPTS;
    const v8h* __restrict__ tf = form + (size_t)(1 - dir) * NPC + (size_t)b * NPTS;

    const int tid  = threadIdx.x;
    const int lane = tid & 63;
    const int w    = tid >> 6;              // wave 0..3, two 32-row strips each
    const int c31  = lane & 31;
    const int rowbase = rb * 256;

    // A fragments: lanes<32 carry k=0..7 (5 live slots); lanes>=32 carry
    // k=8..15 which are all zero.
    v8h a0 = {}, a1 = {};
    if (lane < 32) {
        const _Float16 m2 = (_Float16)(-2.0f);
        v8h f = qf[rowbase + w * 64 + lane];
        a0[0] = m2 * f[0]; a0[1] = m2 * f[1]; a0[2] = m2 * f[2];
        a0[3] = (_Float16)1.0f; a0[4] = f[3];
        f = qf[rowbase + w * 64 + 32 + lane];
        a1[0] = m2 * f[0]; a1[1] = m2 * f[1]; a1[2] = m2 * f[2];
        a1[3] = (_Float16)1.0f; a1[4] = f[3];
    }

    unsigned rm0[16], rm1[16];
#pragma unroll
    for (int r = 0; r < 16; ++r) { rm0[r] = 0x7F7F7F7FU; rm1[r] = 0x7F7F7F7FU; }

    __shared__ v8h bsh[CHUNK];              // 16 KB
    const v16f vzero = {};

    for (int ch = 0; ch < COLS / CHUNK; ++ch) {
        __syncthreads();
        const v8h* __restrict__ g = tf + ch * CHUNK;
#pragma unroll
        for (int k = 0; k < CHUNK / BLOCK; ++k)
            bsh[k * BLOCK + tid] = g[k * BLOCK + tid];   // b128 in, b128 out
        __syncthreads();

#pragma unroll
        for (int cc = 0; cc < CHUNK / 64; ++cc) {
            const v8h b0 = bsh[cc * 64 + c31];           // broadcast b128
            const v8h b1 = bsh[cc * 64 + 32 + c31];
            __builtin_amdgcn_s_setprio(1);
            v16f p0 = MFMA(a0, b0);
            v16f q0 = MFMA(a0, b1);
            v16f p1 = MFMA(a1, b0);
            v16f q1 = MFMA(a1, b1);
            __builtin_amdgcn_s_setprio(0);
#pragma unroll
            for (int r = 0; r < 16; ++r)
                rm0[r] = umin2(rm0[r], umin2(__builtin_bit_cast(unsigned, p0[r]),
                                             __builtin_bit_cast(unsigned, q0[r])));
#pragma unroll
            for (int r = 0; r < 16; ++r)
                rm1[r] = umin2(rm1[r], umin2(__builtin_bit_cast(unsigned, p1[r]),
                                             __builtin_bit_cast(unsigned, q1[r])));
        }
    }

    // Epilogue: butterfly row-min across the 32 lanes sharing each row
    // (rowmins are FINAL: this block saw all 8192 cols), sqrt, block-sum,
    // one u64 fixed-point atomicAdd (order-independent => deterministic).
    float acc = 0.0f;
#pragma unroll
    for (int s = 0; s < 2; ++s) {
#pragma unroll
        for (int r = 0; r < 16; ++r) {
            unsigned u = s ? rm1[r] : rm0[r];
            u = umin2(u, __shfl_xor(u, 1));
            u = umin2(u, __shfl_xor(u, 2));
            u = umin2(u, __shfl_xor(u, 4));
            u = umin2(u, __shfl_xor(u, 8));
            u = umin2(u, __shfl_xor(u, 16));
            if ((lane & 31) == 0) {
                float v = __builtin_bit_cast(float, u);
                acc += sqrtf(fmaxf(fmaxf(v, 0.0f), EPSV));
            }
        }
    }
    acc += __shfl_xor(acc, 32);             // lane 0: this wave's 64 rows

    __syncthreads();                        // safe to reuse bsh
    float* red = (float*)bsh;
    if (lane == 0) red[w] = acc;
    __syncthreads();
    if (tid == 0) {
        float s = red[0] + red[1] + red[2] + red[3];
        unsigned long long fx = (unsigned long long)((double)s * FXSCALE + 0.5);
        atomicAdd(counter, fx);
    }
}

__global__ void chamfer_finalize(
    const unsigned long long* __restrict__ counter, float* __restrict__ out)
{
    out[0] = (float)((double)counter[0] * (1.0 / FXSCALE) / (double)TOTALQ);
}

extern "C" void kernel_launch(void* const* d_in, const int* in_sizes, int n_in,
                              void* d_out, int out_size, void* d_ws, size_t ws_size,
                              hipStream_t stream) {
    const float* xyz1 = (const float*)d_in[0];
    const float* xyz2 = (const float*)d_in[1];
    float* out = (float*)d_out;

    v8h* formbuf = (v8h*)d_ws;                                   // TOTALQ v8h = 2 MB
    unsigned long long* counter = (unsigned long long*)(formbuf + TOTALQ);

    chamfer_prep<<<TOTALQ / 256, 256, 0, stream>>>(xyz1, xyz2, formbuf, counter);
    chamfer_mfma_min<<<2 * NB * 32, BLOCK, 0, stream>>>(formbuf, counter);
    chamfer_finalize<<<1, 1, 0, stream>>>(counter, out);
}